// Round 11
// baseline (116.432 us; speedup 1.0000x reference)
//
#include <hip/hip_runtime.h>
#include <hip/hip_bf16.h>

#define B_ 2
#define N_ 512
#define D_ 64
#define H_ 128
#define OUT_ 64
#define NPAIRS_F 262144.0f   // N_*N_
#define NBLK_ 256            // partial blocks per batch (32 j-tiles x 8 i-tiles)
#define XAS_STRIDE 136       // bf16 elements; 272B row stride (16B aligned)

using bf16x8 = __attribute__((ext_vector_type(8))) __bf16;
using f32x4  = __attribute__((ext_vector_type(4))) float;
using f32x2  = __attribute__((ext_vector_type(2))) float;

// ws layout (bytes):
//   P : float[B*H][256]  @ 0   (262144)  per-block partials (plain stores)

__device__ __forceinline__ bf16x8 pack_bf16x8(f32x4 u0, f32x4 u1) {
    bf16x8 a;
    #pragma unroll
    for (int t = 0; t < 4; t++) { a[t] = (__bf16)u0[t]; a[t + 4] = (__bf16)u1[t]; }
    return a;
}

// interleaved pack: slot 2t = e[t], slot 2t+1 = o[t]
__device__ __forceinline__ bf16x8 pack_ilv(f32x4 e, f32x4 o) {
    bf16x8 a;
    #pragma unroll
    for (int t = 0; t < 4; t++) { a[2 * t] = (__bf16)e[t]; a[2 * t + 1] = (__bf16)o[t]; }
    return a;
}

__device__ __forceinline__ float u2f(unsigned u) {
    union { unsigned u; float f; } c; c.u = u; return c.f;
}

// Transposed weight-tile addressing: element (k,n) of a 128x128 matrix lives
// at wts[n][k] with the 16B k-chunk XOR-swizzled by n's bits 2..5 so that
// fragment reads (lanes = consecutive n, fixed k-chunk) spread banks (~4-way
// instead of 16-way) and staging writes also spread (~4-way).
__device__ __forceinline__ int wt_off(int n, int k) {   // bf16-element offset
    return n * H_ + ((((k >> 3) ^ ((n >> 2) & 15)) << 3) | (k & 7));
}

// Cooperative stage: W (128x128 f32 row-major [k][n]) -> wts (bf16, [n][k]
// swizzled). 16 coalesced f32x4 loads per thread (batched: one latency
// exposure), then 64 ds_write_b16.
__device__ __forceinline__ void stage_wt(const float* __restrict__ W,
                                         __bf16* wts, int tid) {
    f32x4 tmp[16];
    const f32x4* src = (const f32x4*)W;
    #pragma unroll
    for (int rnd = 0; rnd < 16; rnd++) tmp[rnd] = src[rnd * 256 + tid];
    #pragma unroll
    for (int rnd = 0; rnd < 16; rnd++) {
        int idx = rnd * 256 + tid;          // idx = k*32 + nc
        int k = idx >> 5, nc = idx & 31;
        #pragma unroll
        for (int d = 0; d < 4; d++)
            wts[wt_off(4 * nc + d, k)] = (__bf16)tmp[rnd][d];
    }
}

// Fragment read: 8 consecutive k (= chunk ck) at column n, one ds_read_b128.
__device__ __forceinline__ bf16x8 wt_frag(const __bf16* wts, int n, int ck) {
    int ck2 = ck ^ ((n >> 2) & 15);
    union { uint4 u; bf16x8 v; } cv;
    cv.u = *(const uint4*)(wts + n * H_ + ck2 * 8);
    return cv.v;
}

// R10 structure (best: 112.0us) + LDS-staged fragment-ready weights:
// prologue had ~416 scalar global loads per lane (column-walks of W1/W2,
// L2-cold after the ws-poison fill, per-fragment waitcnt exposure ~10-20us).
// Now: stage W1 -> 32KB LDS buffer (transposed bf16) -> read Ba/Bb as b128;
// reuse the SAME buffer for W2 -> read bfrag as b128. 32 coalesced vector
// loads + ~180 LDS ops replace the 416 scalar global loads. Numerics are
// bit-identical to R10 (same f32->bf16 rounding point): absmax must stay 512.
__global__ __launch_bounds__(256, 2) void pair_kernel(
    const float* __restrict__ x, const float* __restrict__ W1,
    const float* __restrict__ b1, const float* __restrict__ W2,
    const float* __restrict__ b2, float* __restrict__ P)
{
    const int tid  = threadIdx.x;
    const int lane = tid & 63;
    const int wid  = tid >> 6;
    const int l15  = lane & 15;
    const int quad = lane >> 4;

    const int j0 = blockIdx.x * 16;
    const int i0 = blockIdx.y * 64;
    const int b  = blockIdx.z;

    __shared__ __bf16 wstage[H_ * H_];       // 32 KB  weight staging (W1 then W2)
    __shared__ __bf16 xbs[64 * H_];          // 16 KB  xb rows i0..i0+64 (bf16)
    __shared__ __bf16 xas[16 * XAS_STRIDE];  // 4.25 KB xa rows j0..j0+16 (bf16)
    __shared__ float  sred[4][H_];           // 2 KB

    const f32x4 zero4 = {0.f, 0.f, 0.f, 0.f};

    // ---- Phase A: x fragments (A-operands), bf16 (4 vector loads) ----
    const float* xiB = x + ((size_t)(b * N_) + i0 + wid * 16 + l15) * D_;
    const float* xjB = x + ((size_t)(b * N_) + j0 + l15) * D_;
    bf16x8 Ai[2], Aj[2];
    #pragma unroll
    for (int s2 = 0; s2 < 2; s2++) {
        const f32x4* pi = (const f32x4*)(xiB + s2 * 32 + quad * 8);
        const f32x4* pj = (const f32x4*)(xjB + s2 * 32 + quad * 8);
        Ai[s2] = pack_bf16x8(pi[0], pi[1]);
        Aj[s2] = pack_bf16x8(pj[0], pj[1]);
    }

    // ---- Stage W1 (transposed bf16) ----
    stage_wt(W1, wstage, tid);
    __syncthreads();                         // w1t visible

    // ---- Phase B: W1 fragments from LDS (one b128 each) ----
    bf16x8 Bb[8][2];   // xb path: all 8 col-tiles, W1 rows 64..127
    #pragma unroll
    for (int ct = 0; ct < 8; ct++)
        #pragma unroll
        for (int s2 = 0; s2 < 2; s2++)
            Bb[ct][s2] = wt_frag(wstage, ct * 16 + l15, 8 + 4 * s2 + quad);
    bf16x8 Ba[2][2];   // xa path: col-tiles 2w, 2w+1, W1 rows 0..63
    #pragma unroll
    for (int e = 0; e < 2; e++)
        #pragma unroll
        for (int s2 = 0; s2 < 2; s2++)
            Ba[e][s2] = wt_frag(wstage, (2 * wid + e) * 16 + l15, 4 * s2 + quad);

    // ---- Phase C: MFMA xa/xb tiles -> LDS (bf16 stores) ----
    // D layout (16x16): col = l15, row = quad*4 + reg.
    #pragma unroll
    for (int ct = 0; ct < 8; ct++) {
        f32x4 acc = zero4;
        acc = __builtin_amdgcn_mfma_f32_16x16x32_bf16(Ai[0], Bb[ct][0], acc, 0, 0, 0);
        acc = __builtin_amdgcn_mfma_f32_16x16x32_bf16(Ai[1], Bb[ct][1], acc, 0, 0, 0);
        #pragma unroll
        for (int reg = 0; reg < 4; reg++)
            xbs[(wid * 16 + quad * 4 + reg) * H_ + ct * 16 + l15] = (__bf16)acc[reg];
    }
    #pragma unroll
    for (int e = 0; e < 2; e++) {
        int ct = 2 * wid + e;
        f32x4 acc = zero4;
        acc = __builtin_amdgcn_mfma_f32_16x16x32_bf16(Aj[0], Ba[e][0], acc, 0, 0, 0);
        acc = __builtin_amdgcn_mfma_f32_16x16x32_bf16(Aj[1], Ba[e][1], acc, 0, 0, 0);
        float bv = b1[ct * 16 + l15];
        #pragma unroll
        for (int reg = 0; reg < 4; reg++)
            xas[(quad * 4 + reg) * XAS_STRIDE + ct * 16 + l15] = (__bf16)(acc[reg] + bv);
    }

    __builtin_amdgcn_sched_barrier(0);
    __syncthreads();   // all w1t reads done; xas/xbs visible

    // ---- Stage W2 into the SAME buffer ----
    stage_wt(W2, wstage, tid);

    // ---- av hoist: unpack this lane's xa row ONCE to f32 (even/odd) ----
    f32x4 avE[4], avO[4];
    #pragma unroll
    for (int s = 0; s < 4; s++) {
        const uint4 raw = *(const uint4*)(xas + l15 * XAS_STRIDE + s * 32 + quad * 8);
        const unsigned rr[4] = {raw.x, raw.y, raw.z, raw.w};
        #pragma unroll
        for (int t = 0; t < 4; t++) {
            avE[s][t] = u2f(rr[t] << 16);
            avO[s][t] = u2f(rr[t] & 0xffff0000u);
        }
    }

    float nb2[8];
    #pragma unroll
    for (int c = 0; c < 8; c++) nb2[c] = -b2[16 * c + l15];

    __syncthreads();                         // w2t visible

    // ---- Phase D: full W2 fragments from LDS (32 x ds_read_b128) ----
    bf16x8 bfrag[8][4];
    #pragma unroll
    for (int c = 0; c < 8; c++)
        #pragma unroll
        for (int s = 0; s < 4; s++)
            bfrag[c][s] = wt_frag(wstage, c * 16 + l15, 4 * s + quad);

    f32x2 csum[8];
    #pragma unroll
    for (int c = 0; c < 8; c++) { csum[c][0] = 0.f; csum[c][1] = 0.f; }

    const __bf16* xrow = xbs + (wid * 16) * H_;

    // ---- main loop: 16 i's; 4 ds_read_b128 per r (bf16), 32 MFMAs ----
    #pragma unroll 2
    for (int r = 0; r < 16; r++) {
        const __bf16* xr = xrow + r * H_;

        bf16x8 afr[4];
        #pragma unroll
        for (int s = 0; s < 4; s++) {
            const uint4 raw = *(const uint4*)(xr + s * 32 + quad * 8);
            const unsigned rr[4] = {raw.x, raw.y, raw.z, raw.w};
            f32x4 e, o;
            #pragma unroll
            for (int t = 0; t < 4; t++) {
                e[t] = u2f(rr[t] << 16);
                o[t] = u2f(rr[t] & 0xffff0000u);
            }
            e = __builtin_elementwise_max(avE[s] + e, zero4);
            o = __builtin_elementwise_max(avO[s] + o, zero4);
            afr[s] = pack_ilv(e, o);
        }

        #pragma unroll
        for (int c = 0; c < 8; c++) {
            f32x4 acc = zero4;
            #pragma unroll
            for (int s = 0; s < 4; s++)
                acc = __builtin_amdgcn_mfma_f32_16x16x32_bf16(afr[s], bfrag[c][s], acc, 0, 0, 0);
            // sum_rows max(acc, -b2)  (the +b2 per-row term is added in tail)
            f32x2 lo; lo[0] = acc[0]; lo[1] = acc[1];
            f32x2 hi; hi[0] = acc[2]; hi[1] = acc[3];
            f32x2 nb; nb[0] = nb2[c]; nb[1] = nb2[c];
            lo = __builtin_elementwise_max(lo, nb);
            hi = __builtin_elementwise_max(hi, nb);
            csum[c] += lo + hi;
        }
    }

    // cross-quad reduction: full column sum for col 16c+l15
    float redv[8];
    #pragma unroll
    for (int c = 0; c < 8; c++) {
        float v = csum[c][0] + csum[c][1];
        v += __shfl_xor(v, 16, 64);
        v += __shfl_xor(v, 32, 64);
        redv[c] = v;
    }

    if (lane < 16) {
        #pragma unroll
        for (int c = 0; c < 8; c++) sred[wid][c * 16 + l15] = redv[c];
    }
    __syncthreads();
    if (tid < H_) {
        float tot = sred[0][tid] + sred[1][tid] + sred[2][tid] + sred[3][tid];
        int id = blockIdx.x * 8 + blockIdx.y;              // 0..255 within batch
        P[((size_t)(b * H_ + tid)) * NBLK_ + id] = tot;    // plain store
    }
}

__global__ __launch_bounds__(128) void tail_kernel(
    const float* __restrict__ P, const float* __restrict__ b2,
    const float* __restrict__ W3, const float* __restrict__ b3,
    const float* __restrict__ V1, const float* __restrict__ c1,
    const float* __restrict__ V2, const float* __restrict__ c2,
    float* __restrict__ out)
{
    __shared__ float Ss[H_], pool[H_], ov[H_];
    const int b = blockIdx.x, t = threadIdx.x;
    // reduce 256 per-block partials for this (b, h)
    const f32x4* Pr = (const f32x4*)(P + ((size_t)(b * H_ + t)) * NBLK_);
    f32x4 s4 = {0.f, 0.f, 0.f, 0.f};
    #pragma unroll 8
    for (int k = 0; k < NBLK_ / 4; k++) s4 += Pr[k];
    // restore the deferred N^2 * b2 term before applying W3
    Ss[t] = (s4[0] + s4[1] + s4[2] + s4[3]) + NPAIRS_F * b2[t];
    __syncthreads();
    float acc = 0.f;
    for (int k = 0; k < H_; k++) acc += Ss[k] * W3[k * H_ + t];
    pool[t] = acc + NPAIRS_F * b3[t];
    __syncthreads();
    acc = c1[t];
    for (int k = 0; k < H_; k++) acc += pool[k] * V1[k * H_ + t];
    ov[t] = acc > 0.f ? acc : 0.f;
    __syncthreads();
    if (t < OUT_) {
        acc = c2[t];
        for (int k = 0; k < H_; k++) acc += ov[k] * V2[k * OUT_ + t];
        out[b * OUT_ + t] = acc;
    }
}

extern "C" void kernel_launch(void* const* d_in, const int* in_sizes, int n_in,
                              void* d_out, int out_size, void* d_ws, size_t ws_size,
                              hipStream_t stream) {
    const float* x  = (const float*)d_in[0];
    const float* W1 = (const float*)d_in[1];
    const float* b1 = (const float*)d_in[2];
    const float* W2 = (const float*)d_in[3];
    const float* b2 = (const float*)d_in[4];
    const float* W3 = (const float*)d_in[5];
    const float* b3 = (const float*)d_in[6];
    const float* V1 = (const float*)d_in[7];
    const float* c1 = (const float*)d_in[8];
    const float* V2 = (const float*)d_in[9];
    const float* c2 = (const float*)d_in[10];
    float* out = (float*)d_out;

    float* P = (float*)d_ws;   // [B*H][256] partials

    dim3 g2(N_ / 16, N_ / 64, B_);   // 32 x 8 x 2 = 512 blocks
    pair_kernel<<<g2, 256, 0, stream>>>(x, W1, b1, W2, b2, P);
    tail_kernel<<<B_, 128, 0, stream>>>(P, b2, W3, b3, V1, c1, V2, c2, out);
}

// Round 12
// 111.868 us; speedup vs baseline: 1.0408x; 1.0408x over previous
//
#include <hip/hip_runtime.h>
#include <hip/hip_bf16.h>

#define B_ 2
#define N_ 512
#define D_ 64
#define H_ 128
#define OUT_ 64
#define NPAIRS_F 262144.0f   // N_*N_
#define NBLK_ 256            // partial blocks per batch (32 j-tiles x 8 i-tiles)
#define XAS_STRIDE 136       // bf16 elements; 272B row stride (16B aligned, bank-spread)

using bf16x8 = __attribute__((ext_vector_type(8))) __bf16;
using f32x4  = __attribute__((ext_vector_type(4))) float;
using f32x2  = __attribute__((ext_vector_type(2))) float;

// ws layout (bytes):
//   P : float[B*H][256]  @ 0   (262144)  per-block partials (plain stores)

__device__ __forceinline__ bf16x8 pack_bf16x8(f32x4 u0, f32x4 u1) {
    bf16x8 a;
    #pragma unroll
    for (int t = 0; t < 4; t++) { a[t] = (__bf16)u0[t]; a[t + 4] = (__bf16)u1[t]; }
    return a;
}

// interleaved pack: slot 2t = e[t], slot 2t+1 = o[t] (compiler fuses to cvt_pk)
__device__ __forceinline__ bf16x8 pack_ilv(f32x4 e, f32x4 o) {
    bf16x8 a;
    #pragma unroll
    for (int t = 0; t < 4; t++) { a[2 * t] = (__bf16)e[t]; a[2 * t + 1] = (__bf16)o[t]; }
    return a;
}

__device__ __forceinline__ float u2f(unsigned u) {
    union { unsigned u; float f; } c; c.u = u; return c.f;
}

// R6 structure + bf16 LDS tiles (best measured: 112.0us, R10):
//   grid 512 blocks (tile 64 i x 16 j), 4 waves, wave = 16-i quarter,
//   full W2 in regs (bfrag[8][4]), occ 2 (reg-bound).
// xbs/xas stored as bf16 -> inner loop does 4 ds_read_b128 per r instead
// of 8 (LDS return-bus relief). Unpack bf16->f32 via shl/and, add f32,
// relu, repack interleaved.
// Epilogue: relu(acc+b2) = max(acc,-b2)+b2; +N^2*b2 restored in tail.
__global__ __launch_bounds__(256, 2) void pair_kernel(
    const float* __restrict__ x, const float* __restrict__ W1,
    const float* __restrict__ b1, const float* __restrict__ W2,
    const float* __restrict__ b2, float* __restrict__ P)
{
    const int tid  = threadIdx.x;
    const int lane = tid & 63;
    const int wid  = tid >> 6;
    const int l15  = lane & 15;
    const int quad = lane >> 4;

    const int j0 = blockIdx.x * 16;
    const int i0 = blockIdx.y * 64;
    const int b  = blockIdx.z;

    __shared__ __bf16 xbs[64 * H_];          // 16 KB  xb rows i0..i0+64 (bf16)
    __shared__ __bf16 xas[16 * XAS_STRIDE];  // 4.25 KB xa rows j0..j0+16 (bf16)
    __shared__ float  sred[4][H_];           // 2 KB

    const f32x4 zero4 = {0.f, 0.f, 0.f, 0.f};

    // ---- Phase A: x fragments (A-operands), bf16 ----
    const float* xiB = x + ((size_t)(b * N_) + i0 + wid * 16 + l15) * D_;
    const float* xjB = x + ((size_t)(b * N_) + j0 + l15) * D_;
    bf16x8 Ai[2], Aj[2];
    #pragma unroll
    for (int s2 = 0; s2 < 2; s2++) {
        const f32x4* pi = (const f32x4*)(xiB + s2 * 32 + quad * 8);
        const f32x4* pj = (const f32x4*)(xjB + s2 * 32 + quad * 8);
        Ai[s2] = pack_bf16x8(pi[0], pi[1]);
        Aj[s2] = pack_bf16x8(pj[0], pj[1]);
    }

    // ---- Phase B: W1 fragments (B-operands) ----
    bf16x8 Bb[8][2];   // xb path: all 8 col-tiles, W1 rows 64..127
    #pragma unroll
    for (int ct = 0; ct < 8; ct++) {
        #pragma unroll
        for (int s2 = 0; s2 < 2; s2++) {
            f32x4 u0, u1;
            #pragma unroll
            for (int t = 0; t < 4; t++) {
                u0[t] = W1[(64 + s2 * 32 + quad * 8 + t) * H_ + ct * 16 + l15];
                u1[t] = W1[(64 + s2 * 32 + quad * 8 + 4 + t) * H_ + ct * 16 + l15];
            }
            Bb[ct][s2] = pack_bf16x8(u0, u1);
        }
    }
    bf16x8 Ba[2][2];   // xa path: col-tiles 2w, 2w+1 spread over 4 waves
    #pragma unroll
    for (int e = 0; e < 2; e++) {
        int ct = 2 * wid + e;
        #pragma unroll
        for (int s2 = 0; s2 < 2; s2++) {
            f32x4 u0, u1;
            #pragma unroll
            for (int t = 0; t < 4; t++) {
                u0[t] = W1[(s2 * 32 + quad * 8 + t) * H_ + ct * 16 + l15];
                u1[t] = W1[(s2 * 32 + quad * 8 + 4 + t) * H_ + ct * 16 + l15];
            }
            Ba[e][s2] = pack_bf16x8(u0, u1);
        }
    }

    // ---- Phase C: MFMA xa/xb tiles -> LDS (bf16 stores) ----
    // D layout (16x16): col = l15, row = quad*4 + reg.
    #pragma unroll
    for (int ct = 0; ct < 8; ct++) {
        f32x4 acc = zero4;
        acc = __builtin_amdgcn_mfma_f32_16x16x32_bf16(Ai[0], Bb[ct][0], acc, 0, 0, 0);
        acc = __builtin_amdgcn_mfma_f32_16x16x32_bf16(Ai[1], Bb[ct][1], acc, 0, 0, 0);
        #pragma unroll
        for (int reg = 0; reg < 4; reg++)
            xbs[(wid * 16 + quad * 4 + reg) * H_ + ct * 16 + l15] = (__bf16)acc[reg];
    }
    #pragma unroll
    for (int e = 0; e < 2; e++) {
        int ct = 2 * wid + e;
        f32x4 acc = zero4;
        acc = __builtin_amdgcn_mfma_f32_16x16x32_bf16(Aj[0], Ba[e][0], acc, 0, 0, 0);
        acc = __builtin_amdgcn_mfma_f32_16x16x32_bf16(Aj[1], Ba[e][1], acc, 0, 0, 0);
        float bv = b1[ct * 16 + l15];
        #pragma unroll
        for (int reg = 0; reg < 4; reg++)
            xas[(quad * 4 + reg) * XAS_STRIDE + ct * 16 + l15] = (__bf16)(acc[reg] + bv);
    }

    // keep prologue frags dead before bfrag goes live
    __builtin_amdgcn_sched_barrier(0);

    // ---- Phase D: full W2 in regs: bfrag[c][s] = W2[k=32s+8q+t][16c+l15] ----
    bf16x8 bfrag[8][4];
    #pragma unroll
    for (int c = 0; c < 8; c++) {
        #pragma unroll
        for (int s = 0; s < 4; s++) {
            f32x4 u0, u1;
            #pragma unroll
            for (int t = 0; t < 4; t++) {
                u0[t] = W2[(s * 32 + quad * 8 + t) * H_ + c * 16 + l15];
                u1[t] = W2[(s * 32 + quad * 8 + 4 + t) * H_ + c * 16 + l15];
            }
            bfrag[c][s] = pack_bf16x8(u0, u1);
        }
    }

    float nb2[8];
    #pragma unroll
    for (int c = 0; c < 8; c++) nb2[c] = -b2[16 * c + l15];

    __syncthreads();                      // xas/xbs visible

    // ---- av hoist: unpack this lane's xa row ONCE to f32 (even/odd split) ----
    f32x4 avE[4], avO[4];
    #pragma unroll
    for (int s = 0; s < 4; s++) {
        const uint4 raw = *(const uint4*)(xas + l15 * XAS_STRIDE + s * 32 + quad * 8);
        const unsigned rr[4] = {raw.x, raw.y, raw.z, raw.w};
        #pragma unroll
        for (int t = 0; t < 4; t++) {
            avE[s][t] = u2f(rr[t] << 16);          // element k=2t   (low half)
            avO[s][t] = u2f(rr[t] & 0xffff0000u);  // element k=2t+1 (high half)
        }
    }

    f32x2 csum[8];
    #pragma unroll
    for (int c = 0; c < 8; c++) { csum[c][0] = 0.f; csum[c][1] = 0.f; }

    const __bf16* xrow = xbs + (wid * 16) * H_;

    // ---- main loop: 16 i's; 4 ds_read_b128 per r (bf16), 32 MFMAs ----
    #pragma unroll 2
    for (int r = 0; r < 16; r++) {
        const __bf16* xr = xrow + r * H_;

        bf16x8 afr[4];
        #pragma unroll
        for (int s = 0; s < 4; s++) {
            const uint4 raw = *(const uint4*)(xr + s * 32 + quad * 8);
            const unsigned rr[4] = {raw.x, raw.y, raw.z, raw.w};
            f32x4 e, o;
            #pragma unroll
            for (int t = 0; t < 4; t++) {
                e[t] = u2f(rr[t] << 16);
                o[t] = u2f(rr[t] & 0xffff0000u);
            }
            e = __builtin_elementwise_max(avE[s] + e, zero4);
            o = __builtin_elementwise_max(avO[s] + o, zero4);
            afr[s] = pack_ilv(e, o);
        }

        #pragma unroll
        for (int c = 0; c < 8; c++) {
            f32x4 acc = zero4;
            #pragma unroll
            for (int s = 0; s < 4; s++)
                acc = __builtin_amdgcn_mfma_f32_16x16x32_bf16(afr[s], bfrag[c][s], acc, 0, 0, 0);
            // sum_rows max(acc, -b2)  (the +b2 per-row term is added in tail)
            f32x2 lo; lo[0] = acc[0]; lo[1] = acc[1];
            f32x2 hi; hi[0] = acc[2]; hi[1] = acc[3];
            f32x2 nb; nb[0] = nb2[c]; nb[1] = nb2[c];
            lo = __builtin_elementwise_max(lo, nb);
            hi = __builtin_elementwise_max(hi, nb);
            csum[c] += lo + hi;
        }
    }

    // cross-quad reduction: full column sum for col 16c+l15
    float redv[8];
    #pragma unroll
    for (int c = 0; c < 8; c++) {
        float v = csum[c][0] + csum[c][1];
        v += __shfl_xor(v, 16, 64);
        v += __shfl_xor(v, 32, 64);
        redv[c] = v;
    }

    if (lane < 16) {
        #pragma unroll
        for (int c = 0; c < 8; c++) sred[wid][c * 16 + l15] = redv[c];
    }
    __syncthreads();
    if (tid < H_) {
        float tot = sred[0][tid] + sred[1][tid] + sred[2][tid] + sred[3][tid];
        int id = blockIdx.x * 8 + blockIdx.y;              // 0..255 within batch
        P[((size_t)(b * H_ + tid)) * NBLK_ + id] = tot;    // plain store
    }
}

__global__ __launch_bounds__(128) void tail_kernel(
    const float* __restrict__ P, const float* __restrict__ b2,
    const float* __restrict__ W3, const float* __restrict__ b3,
    const float* __restrict__ V1, const float* __restrict__ c1,
    const float* __restrict__ V2, const float* __restrict__ c2,
    float* __restrict__ out)
{
    __shared__ float Ss[H_], pool[H_], ov[H_];
    const int b = blockIdx.x, t = threadIdx.x;
    // reduce 256 per-block partials for this (b, h)
    const f32x4* Pr = (const f32x4*)(P + ((size_t)(b * H_ + t)) * NBLK_);
    f32x4 s4 = {0.f, 0.f, 0.f, 0.f};
    #pragma unroll 8
    for (int k = 0; k < NBLK_ / 4; k++) s4 += Pr[k];
    // restore the deferred N^2 * b2 term before applying W3
    Ss[t] = (s4[0] + s4[1] + s4[2] + s4[3]) + NPAIRS_F * b2[t];
    __syncthreads();
    float acc = 0.f;
    for (int k = 0; k < H_; k++) acc += Ss[k] * W3[k * H_ + t];
    pool[t] = acc + NPAIRS_F * b3[t];
    __syncthreads();
    acc = c1[t];
    for (int k = 0; k < H_; k++) acc += pool[k] * V1[k * H_ + t];
    ov[t] = acc > 0.f ? acc : 0.f;
    __syncthreads();
    if (t < OUT_) {
        acc = c2[t];
        for (int k = 0; k < H_; k++) acc += ov[k] * V2[k * OUT_ + t];
        out[b * OUT_ + t] = acc;
    }
}

extern "C" void kernel_launch(void* const* d_in, const int* in_sizes, int n_in,
                              void* d_out, int out_size, void* d_ws, size_t ws_size,
                              hipStream_t stream) {
    const float* x  = (const float*)d_in[0];
    const float* W1 = (const float*)d_in[1];
    const float* b1 = (const float*)d_in[2];
    const float* W2 = (const float*)d_in[3];
    const float* b2 = (const float*)d_in[4];
    const float* W3 = (const float*)d_in[5];
    const float* b3 = (const float*)d_in[6];
    const float* V1 = (const float*)d_in[7];
    const float* c1 = (const float*)d_in[8];
    const float* V2 = (const float*)d_in[9];
    const float* c2 = (const float*)d_in[10];
    float* out = (float*)d_out;

    float* P = (float*)d_ws;   // [B*H][256] partials

    dim3 g2(N_ / 16, N_ / 64, B_);   // 32 x 8 x 2 = 512 blocks
    pair_kernel<<<g2, 256, 0, stream>>>(x, W1, b1, W2, b2, P);
    tail_kernel<<<B_, 128, 0, stream>>>(P, b2, W3, b3, V1, c1, V2, c2, out);
}